// Round 1
// 752.256 us; speedup vs baseline: 1.2212x; 1.2212x over previous
//
#include <hip/hip_runtime.h>

#define BSZ   32768
#define INF   1024
#define UNITS 1024
#define NE    8

using bf16x8 = __attribute__((ext_vector_type(8))) __bf16;
using f32x4  = __attribute__((ext_vector_type(4))) float;

// async global -> LDS, 16B per lane; LDS dest is wave-uniform base + lane*16
#define GLD_LDS16(gp, lp)                                                        \
  __builtin_amdgcn_global_load_lds((__attribute__((address_space(1))) void*)(gp),\
                                   (__attribute__((address_space(3))) void*)(lp),\
                                   16, 0, 0)

// ---------------------------------------------------------------------------
// Prepass 1: alpha (E, IN, UNITS) f32  ->  alphaT (E, UNITS, IN) bf16
// ---------------------------------------------------------------------------
__global__ __launch_bounds__(256) void transpose_cvt(const float* __restrict__ a,
                                                     __bf16* __restrict__ at) {
  __shared__ float tile[32][33];
  const int e  = blockIdx.z;
  const int u0 = blockIdx.x * 32;
  const int i0 = blockIdx.y * 32;
  const float* src = a  + (size_t)e * (INF * UNITS);
  __bf16*      dst = at + (size_t)e * (INF * UNITS);
  const int tx = threadIdx.x & 31, ty = threadIdx.x >> 5;  // 32 x 8
#pragma unroll
  for (int r = 0; r < 32; r += 8)
    tile[ty + r][tx] = src[(size_t)(i0 + ty + r) * UNITS + (u0 + tx)];
  __syncthreads();
#pragma unroll
  for (int r = 0; r < 32; r += 8)
    dst[(size_t)(u0 + ty + r) * INF + (i0 + tx)] = (__bf16)tile[tx][ty + r];
}

// ---------------------------------------------------------------------------
// Prepass 2: x (B, IN) f32 -> xb (B, IN) bf16   (8 elements / thread)
// ---------------------------------------------------------------------------
__global__ __launch_bounds__(256) void cvt_x(const float* __restrict__ x,
                                             __bf16* __restrict__ xb) {
  const size_t i = ((size_t)blockIdx.x * 256 + threadIdx.x) * 8;
  f32x4 a = *(const f32x4*)(x + i);
  f32x4 b = *(const f32x4*)(x + i + 4);
  bf16x8 h;
  h[0] = (__bf16)a.x; h[1] = (__bf16)a.y; h[2] = (__bf16)a.z; h[3] = (__bf16)a.w;
  h[4] = (__bf16)b.x; h[5] = (__bf16)b.y; h[6] = (__bf16)b.z; h[7] = (__bf16)b.w;
  *(bf16x8*)(xb + i) = h;
}

// ---------------------------------------------------------------------------
// 256x256x(BK=64) 8-phase GEMM with Horner gate folding.
//   Invariant after expert e: acc = (sum_{e'<=e} g_e' P_e') / g_e
//   final: out = g7 * acc + sum_e g[b,e]*beta[e,u]
// 512 thr = 8 waves (2M x 4N), per-wave 128x64 output, acc[8][4] f32x4.
// LDS: 4 half-tile slots per operand (128 rows x 64 k bf16, slot = ht&3),
// XOR-swizzled k-chunks (chunk ^= row&7) via pre-swizzled global source +
// swizzled ds_read (linear global_load_lds dest).
// Schedule per iter (tiles kt0=2i, kt1=2i+1; A/B read slots are compile-time
// constants: tile kt0 -> A slot wm, B slot hB; kt1 -> 2+wm, 2+hB):
//   p0: ldB(kt0) ldA q0 | stage A(slot2,kt1,h0) | mfma q0
//   p1:          ldA q1 | stage A(slot3,kt1,h1) | mfma q1
//   p2:          ldA q2 | stage B(slot0,kt0+2,h0) | mfma q2
//   p3:          ldA q3 | stage B(slot1,kt0+2,h1) | vmcnt(4) | mfma q3
//   p4: ldB(kt1) ldA q0 | stage A(slot0,kt0+2,h0) | mfma q0
//   p5:          ldA q1 | stage A(slot1,kt0+2,h1) | mfma q1
//   p6:          ldA q2 | stage B(slot2,kt1+2,h0) | mfma q2
//   p7:          ldA q3 | stage B(slot3,kt1+2,h1) | vmcnt(4) | mfma q3
// Every staged slot's previous occupant finished its reads >=1 barrier before
// the stage issues; vmcnt(4) (2 half-tiles in flight) covers every consumer.
// ---------------------------------------------------------------------------
__global__ __launch_bounds__(512, 2) void gemm_kernel(
    const __bf16* __restrict__ xb, const float* __restrict__ gate,
    const __bf16* __restrict__ aT, const float* __restrict__ beta,
    float* __restrict__ out) {
  __shared__ __align__(16) __bf16 lA[4][128 * 64];   // 64 KiB
  __shared__ __align__(16) __bf16 lB[4][128 * 64];   // 64 KiB
  __shared__ float lG[256 * NE];                     // 8 KiB

  const int t    = threadIdx.x;
  const int wave = t >> 6;
  const int lane = t & 63;
  const int wm   = wave >> 2;        // 0..1  M half
  const int wn   = wave & 3;         // 0..3  N quarter
  const int hB   = wn >> 1;          // which B half this wave reads
  const int fm   = lane & 15;
  const int kq   = lane >> 4;        // 0..3
  const int fq   = kq * 4;           // C/D row-quad base
  const int sw   = fm & 7;           // read-side chunk swizzle (row&7 == fm&7)
  const int bR   = (wn & 1) * 64 + fm;

  // XCD-aware bijective swizzle (512 wgs % 8 == 0), bn-major logical order:
  // each XCD's 64 blocks share one 256-col alphaT panel (4 MiB -> L2).
  const int li = (blockIdx.x & 7) * 64 + (blockIdx.x >> 3);
  const int bn = (li >> 7) * 256;
  const int bm = (li & 127) * 256;

  // stage gates (512 thr x f32x4 = 256 rows x 8)
  *(f32x4*)&lG[t * 4] = *(const f32x4*)&gate[(size_t)bm * NE + t * 4];

  // staging: per half-tile each wave issues 2 calls covering 16 rows.
  // lane -> row (lane>>3), phys chunk (lane&7); global source chunk is
  // (lane&7) ^ (row&7) so that LDS[row][c ^ (row&7)] == global[row][c].
  const int stRow   = wave * 16 + (lane >> 3);
  const int stChunk = ((lane & 7) ^ (lane >> 3)) << 3;  // bf16 elems
  const __bf16* pA  = xb + (size_t)(bm + stRow) * INF + stChunk;
  const __bf16* pB  = aT + (size_t)(bn + stRow) * INF + stChunk;

#define STAGE_A(SLOT, KT, HF)                                                   \
  do {                                                                          \
    const __bf16* s_ = pA + (size_t)(HF) * (128 * INF) + (((KT) & 15) << 6);    \
    GLD_LDS16(s_, &lA[SLOT][(wave * 16) * 64]);                                 \
    GLD_LDS16(s_ + 8 * INF, &lA[SLOT][(wave * 16 + 8) * 64]);                   \
  } while (0)

#define STAGE_B(SLOT, KT, HF)                                                   \
  do {                                                                          \
    const __bf16* s_ = pB + ((size_t)((KT) >> 4) << 20) +                       \
                       (size_t)(HF) * (128 * INF) + (((KT) & 15) << 6);         \
    GLD_LDS16(s_, &lB[SLOT][(wave * 16) * 64]);                                 \
    GLD_LDS16(s_ + 8 * INF, &lB[SLOT][(wave * 16 + 8) * 64]);                   \
  } while (0)

#define LDAF(SLOT, ROW, C) \
  (*(const bf16x8*)&lA[SLOT][((ROW) << 6) + ((((C) ^ sw)) << 3)])
#define LDBF(SLOT, ROW, C) \
  (*(const bf16x8*)&lB[SLOT][((ROW) << 6) + ((((C) ^ sw)) << 3)])

#define LOAD_B(SLOT)                                    \
  _Pragma("unroll") for (int n = 0; n < 4; ++n) {       \
    bq[n][0] = LDBF(SLOT, bR + n * 16, kq);             \
    bq[n][1] = LDBF(SLOT, bR + n * 16, 4 + kq);         \
  }

#define LOAD_A(SLOT, Q)                                        \
  _Pragma("unroll") for (int mm = 0; mm < 2; ++mm) {           \
    aq[mm][0] = LDAF(SLOT, (Q) * 32 + mm * 16 + fm, kq);       \
    aq[mm][1] = LDAF(SLOT, (Q) * 32 + mm * 16 + fm, 4 + kq);   \
  }

#define VMW(N) asm volatile("s_waitcnt vmcnt(" #N ")" ::: "memory")

#define MFMA_BLK(Q)                                                            \
  do {                                                                         \
    __builtin_amdgcn_s_barrier();                                              \
    asm volatile("s_waitcnt lgkmcnt(0)" ::: "memory");                         \
    __builtin_amdgcn_s_setprio(1);                                             \
    _Pragma("unroll") for (int mm = 0; mm < 2; ++mm)                           \
    _Pragma("unroll") for (int n = 0; n < 4; ++n) {                            \
      acc[(Q) * 2 + mm][n] = __builtin_amdgcn_mfma_f32_16x16x32_bf16(          \
          aq[mm][0], bq[n][0], acc[(Q) * 2 + mm][n], 0, 0, 0);                 \
      acc[(Q) * 2 + mm][n] = __builtin_amdgcn_mfma_f32_16x16x32_bf16(          \
          aq[mm][1], bq[n][1], acc[(Q) * 2 + mm][n], 0, 0, 0);                 \
    }                                                                          \
    __builtin_amdgcn_s_setprio(0);                                             \
    __builtin_amdgcn_s_barrier();                                              \
    asm volatile("" ::: "memory");                                             \
  } while (0)

#define RESCALE(E)                                                 \
  do {                                                             \
    _Pragma("unroll") for (int m = 0; m < 8; ++m)                  \
    _Pragma("unroll") for (int r = 0; r < 4; ++r) {                \
      const int rowL  = wm * 128 + m * 16 + fq + r;                \
      const float go  = lG[rowL * NE + (E)-1];                     \
      const float gn  = lG[rowL * NE + (E)];                       \
      const float ra  = go / gn;                                   \
      _Pragma("unroll") for (int n = 0; n < 4; ++n)                \
        acc[m][n][r] *= ra;                                        \
    }                                                              \
  } while (0)

  bf16x8 aq[2][2], bq[4][2];
  f32x4  acc[8][4] = {};

  // ---- prologue: B-ht0,B-ht1,A-ht0,A-ht1,B-ht2,B-ht3 (12 loads/thread) ----
  STAGE_B(0, 0, 0); STAGE_B(1, 0, 1);
  STAGE_A(0, 0, 0); STAGE_A(1, 0, 1);
  STAGE_B(2, 1, 0); STAGE_B(3, 1, 1);
  asm volatile("s_waitcnt vmcnt(4) lgkmcnt(0)" ::: "memory");  // tile0 landed + lG visible
  __builtin_amdgcn_s_barrier();
  asm volatile("" ::: "memory");

#pragma unroll 1
  for (int i = 0; i < 63; ++i) {
    if (i && !(i & 7)) RESCALE(i >> 3);  // expert boundary (8 iters/expert)
    const int kt1 = 2 * i + 1, ktn = 2 * i + 2, ktn1 = 2 * i + 3;
    LOAD_B(hB);     LOAD_A(wm, 0);     STAGE_A(2, kt1, 0);           MFMA_BLK(0);
                    LOAD_A(wm, 1);     STAGE_A(3, kt1, 1);           MFMA_BLK(1);
                    LOAD_A(wm, 2);     STAGE_B(0, ktn, 0);           MFMA_BLK(2);
                    LOAD_A(wm, 3);     STAGE_B(1, ktn, 1);  VMW(4);  MFMA_BLK(3);
    LOAD_B(2 + hB); LOAD_A(2 + wm, 0); STAGE_A(0, ktn, 0);           MFMA_BLK(0);
                    LOAD_A(2 + wm, 1); STAGE_A(1, ktn, 1);           MFMA_BLK(1);
                    LOAD_A(2 + wm, 2); STAGE_B(2, ktn1, 0);          MFMA_BLK(2);
                    LOAD_A(2 + wm, 3); STAGE_B(3, ktn1, 1); VMW(4);  MFMA_BLK(3);
  }
  {  // ---- i = 63 peeled: no staging past p1; tight waits ----
    LOAD_B(hB);     LOAD_A(wm, 0);     STAGE_A(2, 127, 0);           MFMA_BLK(0);
                    LOAD_A(wm, 1);     STAGE_A(3, 127, 1);           MFMA_BLK(1);
                    LOAD_A(wm, 2);                                   MFMA_BLK(2);
                    LOAD_A(wm, 3);                          VMW(0);  MFMA_BLK(3);
    LOAD_B(2 + hB); LOAD_A(2 + wm, 0);                               MFMA_BLK(0);
                    LOAD_A(2 + wm, 1);                               MFMA_BLK(1);
                    LOAD_A(2 + wm, 2);                               MFMA_BLK(2);
                    LOAD_A(2 + wm, 3);                               MFMA_BLK(3);
  }

  // ---- epilogue: out = g7*acc + sum_e g[b,e]*beta[e,u] ----
  float bcol[4][NE];
#pragma unroll
  for (int n = 0; n < 4; ++n) {
    const int u = bn + wn * 64 + n * 16 + fm;
#pragma unroll
    for (int e2 = 0; e2 < NE; ++e2) bcol[n][e2] = beta[e2 * UNITS + u];
  }
#pragma unroll
  for (int m = 0; m < 8; ++m) {
#pragma unroll
    for (int r = 0; r < 4; ++r) {
      const int rowL = wm * 128 + m * 16 + fq + r;
      const int b    = bm + rowL;
      float g8[NE];
#pragma unroll
      for (int e2 = 0; e2 < NE; ++e2) g8[e2] = lG[rowL * NE + e2];
#pragma unroll
      for (int n = 0; n < 4; ++n) {
        float bias = 0.f;
#pragma unroll
        for (int e2 = 0; e2 < NE; ++e2) bias += g8[e2] * bcol[n][e2];
        const int u = bn + wn * 64 + n * 16 + fm;
        out[(size_t)b * UNITS + u] = g8[7] * acc[m][n][r] + bias;
      }
    }
  }
}

// ---------------------------------------------------------------------------
extern "C" void kernel_launch(void* const* d_in, const int* in_sizes, int n_in,
                              void* d_out, int out_size, void* d_ws, size_t ws_size,
                              hipStream_t stream) {
  const float* x     = (const float*)d_in[0];  // (B, IN)
  const float* gate  = (const float*)d_in[1];  // (B, E)
  const float* alpha = (const float*)d_in[2];  // (E, IN, UNITS)
  const float* beta  = (const float*)d_in[3];  // (E, UNITS)
  float* out         = (float*)d_out;          // (B, UNITS)
  __bf16* aT  = (__bf16*)d_ws;                                     // 16 MiB
  __bf16* xbp = (__bf16*)((char*)d_ws + (size_t)16 * 1024 * 1024); // 64 MiB

  transpose_cvt<<<dim3(UNITS / 32, INF / 32, NE), 256, 0, stream>>>(alpha, aT);
  cvt_x<<<dim3(BSZ * INF / (256 * 8)), 256, 0, stream>>>(x, xbp);
  gemm_kernel<<<dim3(512), 512, 0, stream>>>(xbp, gate, aT, beta, out);
}